// Round 15
// baseline (850.113 us; speedup 1.0000x reference)
//
#include <hip/hip_runtime.h>

#define D 128

typedef short v8s __attribute__((ext_vector_type(8)));
typedef float v4f __attribute__((ext_vector_type(4)));

// fp32 -> bf16 hi/lo split: f ~= hi + lo, |err| ~ 2^-17 * |f|
__device__ __forceinline__ void f2hl(float f, unsigned short& h, unsigned short& l) {
    unsigned int u = __float_as_uint(f);
    unsigned int hu = u & 0xffff0000u;
    float lf = f - __uint_as_float(hu);          // exact
    h = (unsigned short)(hu >> 16);
    l = (unsigned short)((__float_as_uint(lf) + 0x8000u) >> 16);  // round
}

// permuted column position for a 4-aligned k chunk (MFMA A-frag contiguous layout)
// k = 4g + (e&3) + 16*(e>>2)  <->  p = 8g + e   (within each 32-wide k block)
__device__ __forceinline__ int permc(int c) {
    return (c & ~31) + ((c & 12) << 1) + ((c & 16) >> 2);
}

// ---------------- preprocessing ----------------

__global__ void k_count(const int* __restrict__ dst, int* __restrict__ deg, int E) {
    int e = blockIdx.x * 256 + threadIdx.x;
    if (e < E) atomicAdd(&deg[dst[e]], 1);
}

__global__ __launch_bounds__(256) void k_blocksum(const int* __restrict__ deg,
                                                  int* __restrict__ bsums, int N) {
    __shared__ int s[256];
    int base = blockIdx.x * 1024 + threadIdx.x * 4;
    int v = 0;
#pragma unroll
    for (int j = 0; j < 4; ++j) { int i = base + j; if (i < N) v += deg[i]; }
    s[threadIdx.x] = v;
    __syncthreads();
    for (int off = 128; off > 0; off >>= 1) {
        if (threadIdx.x < off) s[threadIdx.x] += s[threadIdx.x + off];
        __syncthreads();
    }
    if (threadIdx.x == 0) bsums[blockIdx.x] = s[0];
}

__global__ __launch_bounds__(256) void k_scanbsums(int* __restrict__ bsums, int NB) {
    __shared__ int s[256];
    __shared__ int carry;
    int t = threadIdx.x;
    if (t == 0) carry = 0;
    __syncthreads();
    for (int base = 0; base < NB; base += 256) {
        int i = base + t;
        int v = (i < NB) ? bsums[i] : 0;
        s[t] = v;
        __syncthreads();
        for (int off = 1; off < 256; off <<= 1) {
            int x = (t >= off) ? s[t - off] : 0;
            __syncthreads();
            s[t] += x;
            __syncthreads();
        }
        if (i < NB) bsums[i] = carry + s[t] - v;   // exclusive
        __syncthreads();
        if (t == 0) carry += s[255];
        __syncthreads();
    }
}

__global__ __launch_bounds__(256) void k_scan2(const int* __restrict__ deg,
                                               const int* __restrict__ bsums,
                                               int* __restrict__ rowst,
                                               float* __restrict__ dinv, int N) {
    __shared__ int s[256];
    int t = threadIdx.x;
    int base = blockIdx.x * 1024 + t * 4;
    int v[4];
#pragma unroll
    for (int j = 0; j < 4; ++j) { int i = base + j; v[j] = (i < N) ? deg[i] : 0; }
    int tsum = v[0] + v[1] + v[2] + v[3];
    s[t] = tsum;
    __syncthreads();
    for (int off = 1; off < 256; off <<= 1) {
        int x = (t >= off) ? s[t - off] : 0;
        __syncthreads();
        s[t] += x;
        __syncthreads();
    }
    int run = s[t] - tsum + bsums[blockIdx.x];
#pragma unroll
    for (int j = 0; j < 4; ++j) {
        int i = base + j;
        if (i < N) {
            rowst[i] = run;
            dinv[i] = rsqrtf((float)(v[j] + 1));   // +1 for self-loop
        }
        run += v[j];
    }
}

__global__ void k_fill(const int* __restrict__ src, const int* __restrict__ dst,
                       const int* __restrict__ rowst, int* __restrict__ cursor,
                       const float* __restrict__ dinv, int2* __restrict__ csr, int E) {
    int e = blockIdx.x * 256 + threadIdx.x;
    if (e >= E) return;
    int s = src[e], d = dst[e];
    int p = rowst[d] + atomicAdd(&cursor[d], 1);
    csr[p] = make_int2(s, __float_as_int(dinv[s] * dinv[d]));
}

// ---------------- weight fragment packing ----------------

// Ws[9][128][128] fp32 -> per-lane MFMA B fragments, hi/lo bf16:
// wf[((l*4+ks)*8+nt)*64 + lane][8 words]: words 0-3 = hi frag, 4-7 = lo frag
__global__ __launch_bounds__(64) void k_wconv(const float* __restrict__ Ws,
                                              unsigned int* __restrict__ wf) {
    int b = blockIdx.x;              // l*32 + ks*8 + nt
    int l = b >> 5, ks = (b >> 3) & 3, nt = b & 7;
    int lane = threadIdx.x;
    int g = lane >> 4, c = (lane & 15) + nt * 16;
    const float* W = Ws + (size_t)l * D * D;
    unsigned int hw[4], lw[4];
#pragma unroll
    for (int w = 0; w < 4; ++w) {
        unsigned short hs[2], ls[2];
#pragma unroll
        for (int j = 0; j < 2; ++j) {
            int e = 2 * w + j;
            int k = ks * 32 + 4 * g + (e & 3) + 16 * (e >> 2);
            f2hl(W[k * D + c], hs[j], ls[j]);
        }
        hw[w] = (unsigned int)hs[0] | ((unsigned int)hs[1] << 16);
        lw[w] = (unsigned int)ls[0] | ((unsigned int)ls[1] << 16);
    }
    unsigned int* dstp = wf + ((size_t)((l * 4 + ks) * 8 + nt) * 64 + lane) * 8;
    *(uint4*)dstp = make_uint4(hw[0], hw[1], hw[2], hw[3]);
    *(uint4*)(dstp + 4) = make_uint4(lw[0], lw[1], lw[2], lw[3]);
}

// ---------------- fused hidden layer: hout = relu( (A_norm . hin) @ W + b ) --------
// 64-node tile per 512-thread block. Phase 1: 16 groups of 32 lanes pull nodes from
// an LDS work queue (first 16 static) -- dynamic balance kills the barrier's
// max-of-stragglers tax; per-node walk is the proven unbroken unroll-4 pipeline.
// Epilogue converts fp32->bf16 hi/lo once, stores packed planes to LDS.
// Phase 2: 8 waves x (4 row tiles x 2 col halves), pure MFMA, phase-local W loads.

#define EDGE_FMA(ACC, EW, R)                                               \
    {                                                                      \
        float w_ = __int_as_float(EW);                                     \
        ACC.x = fmaf(w_, (R).x, ACC.x); ACC.y = fmaf(w_, (R).y, ACC.y);    \
        ACC.z = fmaf(w_, (R).z, ACC.z); ACC.w = fmaf(w_, (R).w, ACC.w);    \
    }

__global__ __launch_bounds__(512, 8) void k_fused(const float* __restrict__ hin,
                                                  const int2* __restrict__ csr,
                                                  const int* __restrict__ rowst,
                                                  const int* __restrict__ deg,
                                                  const float* __restrict__ dinv,
                                                  const unsigned int* __restrict__ wf,
                                                  const float* __restrict__ bias,
                                                  float* __restrict__ hout, int N) {
    __shared__ unsigned int sHi[64 * 64];    // 16 KB bf16-hi plane (64 rows x 64 uints)
    __shared__ unsigned int sLo[64 * 64];    // 16 KB bf16-lo plane
    __shared__ int sCtr;
    const int nb = blockIdx.x * 64;

    if (threadIdx.x == 0) sCtr = 16;
    __syncthreads();

    // ---- phase 1: groups pull nodes dynamically; one node at a time ----
    {
        const int gp = threadIdx.x >> 5;     // 0..15
        const int l32 = threadIdx.x & 31;
        const int c = l32 << 2;
        const int p0 = permc(c);
        int s = gp;                          // first 16 rows statically assigned
        while (s < 64) {
            int node = nb + s;
            if (node < N) {
                float di = dinv[node];
                float s2 = di * di;
                float4 t0 = *(const float4*)&hin[(size_t)node * D + c];
                float4 acc;
                acc.x = s2 * t0.x; acc.y = s2 * t0.y;
                acc.z = s2 * t0.z; acc.w = s2 * t0.w;

                int s0 = rowst[node];
                int cnt = deg[node];
                int j = 0;
                for (; j + 4 <= cnt; j += 4) {
                    int2 e0 = csr[s0 + j + 0];
                    int2 e1 = csr[s0 + j + 1];
                    int2 e2 = csr[s0 + j + 2];
                    int2 e3 = csr[s0 + j + 3];
                    float4 r0 = *(const float4*)&hin[(size_t)e0.x * D + c];
                    float4 r1 = *(const float4*)&hin[(size_t)e1.x * D + c];
                    float4 r2 = *(const float4*)&hin[(size_t)e2.x * D + c];
                    float4 r3 = *(const float4*)&hin[(size_t)e3.x * D + c];
                    EDGE_FMA(acc, e0.y, r0);
                    EDGE_FMA(acc, e1.y, r1);
                    EDGE_FMA(acc, e2.y, r2);
                    EDGE_FMA(acc, e3.y, r3);
                }
                for (; j < cnt; ++j) {
                    int2 e = csr[s0 + j];
                    float4 r = *(const float4*)&hin[(size_t)e.x * D + c];
                    EDGE_FMA(acc, e.y, r);
                }
                // one-time fp32 -> bf16 hi/lo conversion, packed LDS store
                unsigned short h0, l0, h1, l1, h2, l2, h3, l3;
                f2hl(acc.x, h0, l0); f2hl(acc.y, h1, l1);
                f2hl(acc.z, h2, l2); f2hl(acc.w, h3, l3);
                unsigned int hw0 = (unsigned int)h0 | ((unsigned int)h1 << 16);
                unsigned int hw1 = (unsigned int)h2 | ((unsigned int)h3 << 16);
                unsigned int lw0 = (unsigned int)l0 | ((unsigned int)l1 << 16);
                unsigned int lw1 = (unsigned int)l2 | ((unsigned int)l3 << 16);
                int u = (p0 >> 1) ^ ((s & 7) << 2);
                *(uint2*)&sHi[s * 64 + u] = make_uint2(hw0, hw1);
                *(uint2*)&sLo[s * 64 + u] = make_uint2(lw0, lw1);
            }
            // pull next node from the block queue
            int nxt;
            if (l32 == 0) nxt = atomicAdd(&sCtr, 1);
            nxt = __shfl(nxt, 0, 32);
            s = nxt;
        }
    }
    __syncthreads();

    // ---- phase 2: pure-MFMA, 8 waves cover 64 rows x 128 cols ----
    const int w = threadIdx.x >> 6;          // wave id (0..7)
    const int lane = threadIdx.x & 63;
    const int q = lane & 15, g = lane >> 4;
    const int rtile = w & 3;                 // 16-row tile
    const int cgp = w >> 2;                  // column half (4 col tiles each)
    const int row = rtile * 16 + q;

    v4f acc[4];
#pragma unroll
    for (int nt = 0; nt < 4; ++nt) acc[nt] = (v4f)0.f;

    const int sw2 = (q & 7) << 2;

#pragma unroll
    for (int ks = 0; ks < 4; ++ks) {
        int u0 = (ks * 16 + g * 4) ^ sw2;
        v8s ah = *(const v8s*)&sHi[row * 64 + u0];
        v8s al = *(const v8s*)&sLo[row * 64 + u0];
#pragma unroll
        for (int nt = 0; nt < 4; ++nt) {
            const unsigned int* wk = wf + ((size_t)(ks * 8 + cgp * 4 + nt) * 64 + lane) * 8;
            v8s wh = *(const v8s*)(wk);
            v8s wl = *(const v8s*)(wk + 4);
            acc[nt] = __builtin_amdgcn_mfma_f32_16x16x32_bf16(ah, wh, acc[nt], 0, 0, 0);
            acc[nt] = __builtin_amdgcn_mfma_f32_16x16x32_bf16(al, wh, acc[nt], 0, 0, 0);
            acc[nt] = __builtin_amdgcn_mfma_f32_16x16x32_bf16(ah, wl, acc[nt], 0, 0, 0);
        }
    }

    // ---- epilogue: bias + ReLU, store. C/D layout: col = q, row = 4g + i ----
    const int growb = nb + rtile * 16 + 4 * g;
#pragma unroll
    for (int nt = 0; nt < 4; ++nt) {
        const int col = (cgp * 4 + nt) * 16 + q;
        const float bv = bias[col];
#pragma unroll
        for (int i = 0; i < 4; ++i) {
            int grow = growb + i;
            if (grow < N) {
                float v = fmaxf(acc[nt][i] + bv, 0.f);
                hout[(size_t)grow * D + col] = v;
            }
        }
    }
}

// ---------------- head: T16 = H @ Wo, then Out = A_norm . T16 + bo ----------------

__global__ __launch_bounds__(256) void k_gemm_out(const float* __restrict__ A,
                                                  const float* __restrict__ Wo,
                                                  float* __restrict__ Out, int M) {
    __shared__ float sW[128 * 16];
    for (int i = threadIdx.x * 4; i < 2048; i += 1024)
        *(float4*)&sW[i] = *(const float4*)&Wo[i];
    __syncthreads();
    int r = blockIdx.x * 16 + (threadIdx.x >> 4);
    int c = threadIdx.x & 15;
    if (r >= M) return;
    const float* arow = A + (size_t)r * D;
    float acc = 0.f;
#pragma unroll
    for (int k4 = 0; k4 < 32; ++k4) {
        float4 h = *(const float4*)&arow[k4 * 4];
        acc = fmaf(h.x, sW[(k4 * 4 + 0) * 16 + c], acc);
        acc = fmaf(h.y, sW[(k4 * 4 + 1) * 16 + c], acc);
        acc = fmaf(h.z, sW[(k4 * 4 + 2) * 16 + c], acc);
        acc = fmaf(h.w, sW[(k4 * 4 + 3) * 16 + c], acc);
    }
    Out[(size_t)r * 16 + c] = acc;
}

__global__ __launch_bounds__(256) void k_aggr_out(const float* __restrict__ T16,
                                                  const int2* __restrict__ csr,
                                                  const int* __restrict__ rowst,
                                                  const int* __restrict__ deg,
                                                  const float* __restrict__ dinv,
                                                  const float* __restrict__ bias,
                                                  float* __restrict__ Out, int N) {
    int node = blockIdx.x * 16 + (threadIdx.x >> 4);
    int c = threadIdx.x & 15;
    if (node >= N) return;
    float di = dinv[node];
    float acc = fmaf(di * di, T16[(size_t)node * 16 + c], bias[c]);
    int s0 = rowst[node];
    int cnt = deg[node];
    int j = 0;
    for (; j + 4 <= cnt; j += 4) {
        int2 e0 = csr[s0 + j + 0];
        int2 e1 = csr[s0 + j + 1];
        int2 e2 = csr[s0 + j + 2];
        int2 e3 = csr[s0 + j + 3];
        float r0 = T16[(size_t)e0.x * 16 + c];
        float r1 = T16[(size_t)e1.x * 16 + c];
        float r2 = T16[(size_t)e2.x * 16 + c];
        float r3 = T16[(size_t)e3.x * 16 + c];
        acc = fmaf(__int_as_float(e0.y), r0, acc);
        acc = fmaf(__int_as_float(e1.y), r1, acc);
        acc = fmaf(__int_as_float(e2.y), r2, acc);
        acc = fmaf(__int_as_float(e3.y), r3, acc);
    }
    for (; j < cnt; ++j) {
        int2 e = csr[s0 + j];
        acc = fmaf(__int_as_float(e.y), T16[(size_t)e.x * 16 + c], acc);
    }
    Out[(size_t)node * 16 + c] = acc;
}

// ---------------- launch ----------------

extern "C" void kernel_launch(void* const* d_in, const int* in_sizes, int n_in,
                              void* d_out, int out_size, void* d_ws, size_t ws_size,
                              hipStream_t stream) {
    const float* x  = (const float*)d_in[0];
    const int*   ei = (const int*)d_in[1];
    const float* Ws = (const float*)d_in[2];
    const float* bs = (const float*)d_in[3];
    const float* Wo = (const float*)d_in[4];
    const float* bo = (const float*)d_in[5];
    float* out = (float*)d_out;

    const int N = in_sizes[0] / D;     // 100000
    const int E = in_sizes[1] / 2;     // 600000
    const int* src = ei;
    const int* dst = ei + E;

    // workspace layout (~109.4 MB)
    float* H0     = (float*)d_ws;                     // N*128 fp32 ping
    float* H1     = H0 + (size_t)N * D;               // N*128 fp32 pong
    int*   deg    = (int*)(H1 + (size_t)N * D);
    int*   cursor = deg + N;
    int*   rowst  = cursor + N;
    float* dinv   = (float*)(rowst + N);
    int*   bsums  = (int*)(dinv + N);
    int2*  csr    = (int2*)(bsums + 1024);
    unsigned int* wfrag = (unsigned int*)(csr + E);   // 9 * 16384 uints (576 KB)

    const int NB = (N + 1023) / 1024;

    hipMemsetAsync(deg, 0, (size_t)2 * N * sizeof(int), stream);  // deg + cursor
    k_count<<<(E + 255) / 256, 256, 0, stream>>>(dst, deg, E);
    k_blocksum<<<NB, 256, 0, stream>>>(deg, bsums, N);
    k_scanbsums<<<1, 256, 0, stream>>>(bsums, NB);
    k_scan2<<<NB, 256, 0, stream>>>(deg, bsums, rowst, dinv, N);
    k_fill<<<(E + 255) / 256, 256, 0, stream>>>(src, dst, rowst, cursor, dinv, csr, E);

    k_wconv<<<288, 64, 0, stream>>>(Ws, wfrag);

    const float* hin = x;
    float* hout = H0;
    const int gblk64 = (N + 63) / 64;
    for (int l = 0; l < 9; ++l) {
        k_fused<<<gblk64, 512, 0, stream>>>(hin, csr, rowst, deg, dinv,
                                            wfrag + (size_t)l * 16384,
                                            bs + (size_t)l * D, hout, N);
        hin = hout;
        hout = (hout == H0) ? H1 : H0;
    }
    // head: transform-then-aggregate (16-wide gather, 8x fewer bytes)
    float* T16 = hout;                 // reuse the other ping-pong buffer
    k_gemm_out<<<(N + 15) / 16, 256, 0, stream>>>(hin, Wo, T16, N);
    k_aggr_out<<<(N + 15) / 16, 256, 0, stream>>>(T16, csr, rowst, deg, dinv, bo, out, N);
}

// Round 17
// 785.057 us; speedup vs baseline: 1.0829x; 1.0829x over previous
//
#include <hip/hip_runtime.h>

#define D 128

typedef short v8s __attribute__((ext_vector_type(8)));
typedef float v4f __attribute__((ext_vector_type(4)));

// fp32 -> bf16 hi/lo split: f ~= hi + lo, |err| ~ 2^-17 * |f|
__device__ __forceinline__ void f2hl(float f, unsigned short& h, unsigned short& l) {
    unsigned int u = __float_as_uint(f);
    unsigned int hu = u & 0xffff0000u;
    float lf = f - __uint_as_float(hu);          // exact
    h = (unsigned short)(hu >> 16);
    l = (unsigned short)((__float_as_uint(lf) + 0x8000u) >> 16);  // round
}

// permuted column position for a 4-aligned k chunk (MFMA A-frag contiguous layout)
// k = 4g + (e&3) + 16*(e>>2)  <->  p = 8g + e   (within each 32-wide k block)
__device__ __forceinline__ int permc(int c) {
    return (c & ~31) + ((c & 12) << 1) + ((c & 16) >> 2);
}

// ---------------- preprocessing ----------------

__global__ void k_count(const int* __restrict__ dst, int* __restrict__ deg, int E) {
    int e = blockIdx.x * 256 + threadIdx.x;
    if (e < E) atomicAdd(&deg[dst[e]], 1);
}

__global__ __launch_bounds__(256) void k_blocksum(const int* __restrict__ deg,
                                                  int* __restrict__ bsums, int N) {
    __shared__ int s[256];
    int base = blockIdx.x * 1024 + threadIdx.x * 4;
    int v = 0;
#pragma unroll
    for (int j = 0; j < 4; ++j) { int i = base + j; if (i < N) v += deg[i]; }
    s[threadIdx.x] = v;
    __syncthreads();
    for (int off = 128; off > 0; off >>= 1) {
        if (threadIdx.x < off) s[threadIdx.x] += s[threadIdx.x + off];
        __syncthreads();
    }
    if (threadIdx.x == 0) bsums[blockIdx.x] = s[0];
}

__global__ __launch_bounds__(256) void k_scanbsums(int* __restrict__ bsums, int NB) {
    __shared__ int s[256];
    __shared__ int carry;
    int t = threadIdx.x;
    if (t == 0) carry = 0;
    __syncthreads();
    for (int base = 0; base < NB; base += 256) {
        int i = base + t;
        int v = (i < NB) ? bsums[i] : 0;
        s[t] = v;
        __syncthreads();
        for (int off = 1; off < 256; off <<= 1) {
            int x = (t >= off) ? s[t - off] : 0;
            __syncthreads();
            s[t] += x;
            __syncthreads();
        }
        if (i < NB) bsums[i] = carry + s[t] - v;   // exclusive
        __syncthreads();
        if (t == 0) carry += s[255];
        __syncthreads();
    }
}

__global__ __launch_bounds__(256) void k_scan2(const int* __restrict__ deg,
                                               const int* __restrict__ bsums,
                                               int* __restrict__ rowst,
                                               float* __restrict__ dinv, int N) {
    __shared__ int s[256];
    int t = threadIdx.x;
    int base = blockIdx.x * 1024 + t * 4;
    int v[4];
#pragma unroll
    for (int j = 0; j < 4; ++j) { int i = base + j; v[j] = (i < N) ? deg[i] : 0; }
    int tsum = v[0] + v[1] + v[2] + v[3];
    s[t] = tsum;
    __syncthreads();
    for (int off = 1; off < 256; off <<= 1) {
        int x = (t >= off) ? s[t - off] : 0;
        __syncthreads();
        s[t] += x;
        __syncthreads();
    }
    int run = s[t] - tsum + bsums[blockIdx.x];
#pragma unroll
    for (int j = 0; j < 4; ++j) {
        int i = base + j;
        if (i < N) {
            rowst[i] = run;
            dinv[i] = rsqrtf((float)(v[j] + 1));   // +1 for self-loop
        }
        run += v[j];
    }
}

__global__ void k_fill(const int* __restrict__ src, const int* __restrict__ dst,
                       const int* __restrict__ rowst, int* __restrict__ cursor,
                       const float* __restrict__ dinv, int2* __restrict__ csr, int E) {
    int e = blockIdx.x * 256 + threadIdx.x;
    if (e >= E) return;
    int s = src[e], d = dst[e];
    int p = rowst[d] + atomicAdd(&cursor[d], 1);
    csr[p] = make_int2(s, __float_as_int(dinv[s] * dinv[d]));
}

// ---------------- weight fragment packing ----------------

// Ws[9][128][128] fp32 -> per-lane MFMA B fragments, hi/lo bf16:
// wf[((l*4+ks)*8+nt)*64 + lane][8 words]: words 0-3 = hi frag, 4-7 = lo frag
__global__ __launch_bounds__(64) void k_wconv(const float* __restrict__ Ws,
                                              unsigned int* __restrict__ wf) {
    int b = blockIdx.x;              // l*32 + ks*8 + nt
    int l = b >> 5, ks = (b >> 3) & 3, nt = b & 7;
    int lane = threadIdx.x;
    int g = lane >> 4, c = (lane & 15) + nt * 16;
    const float* W = Ws + (size_t)l * D * D;
    unsigned int hw[4], lw[4];
#pragma unroll
    for (int w = 0; w < 4; ++w) {
        unsigned short hs[2], ls[2];
#pragma unroll
        for (int j = 0; j < 2; ++j) {
            int e = 2 * w + j;
            int k = ks * 32 + 4 * g + (e & 3) + 16 * (e >> 2);
            f2hl(W[k * D + c], hs[j], ls[j]);
        }
        hw[w] = (unsigned int)hs[0] | ((unsigned int)hs[1] << 16);
        lw[w] = (unsigned int)ls[0] | ((unsigned int)ls[1] << 16);
    }
    unsigned int* dstp = wf + ((size_t)((l * 4 + ks) * 8 + nt) * 64 + lane) * 8;
    *(uint4*)dstp = make_uint4(hw[0], hw[1], hw[2], hw[3]);
    *(uint4*)(dstp + 4) = make_uint4(lw[0], lw[1], lw[2], lw[3]);
}

// ---------------- fused hidden layer: hout = relu( (A_norm . hin) @ W + b ) --------
// 64-node tile per 512-thread block. Phase 1: 16 groups of 32 lanes pull nodes from
// an LDS work queue (first 16 static); per-node walk is the unbroken unroll-4
// pipeline; epilogue converts fp32->bf16 hi/lo once, stores packed planes to LDS.
// Phase 2: 8 waves; wave w owns col tile w for ALL 4 row tiles -- W fragments are
// loaded ONCE per ks and reused 4x (4x less W L2 traffic than 16-row variants).

#define EDGE_FMA(ACC, EW, R)                                               \
    {                                                                      \
        float w_ = __int_as_float(EW);                                     \
        ACC.x = fmaf(w_, (R).x, ACC.x); ACC.y = fmaf(w_, (R).y, ACC.y);    \
        ACC.z = fmaf(w_, (R).z, ACC.z); ACC.w = fmaf(w_, (R).w, ACC.w);    \
    }

__global__ __launch_bounds__(512, 8) void k_fused(const float* __restrict__ hin,
                                                  const int2* __restrict__ csr,
                                                  const int* __restrict__ rowst,
                                                  const int* __restrict__ deg,
                                                  const float* __restrict__ dinv,
                                                  const unsigned int* __restrict__ wf,
                                                  const float* __restrict__ bias,
                                                  float* __restrict__ hout, int N) {
    __shared__ unsigned int sHi[64 * 64];    // 16 KB bf16-hi plane (64 rows x 64 uints)
    __shared__ unsigned int sLo[64 * 64];    // 16 KB bf16-lo plane
    __shared__ int sCtr;
    const int nb = blockIdx.x * 64;

    if (threadIdx.x == 0) sCtr = 16;
    __syncthreads();

    // ---- phase 1: groups pull nodes dynamically; one node at a time ----
    {
        const int gp = threadIdx.x >> 5;     // 0..15
        const int l32 = threadIdx.x & 31;
        const int c = l32 << 2;
        const int p0 = permc(c);
        int s = gp;                          // first 16 rows statically assigned
        while (s < 64) {
            int node = nb + s;
            if (node < N) {
                float di = dinv[node];
                float s2 = di * di;
                float4 t0 = *(const float4*)&hin[(size_t)node * D + c];
                float4 acc;
                acc.x = s2 * t0.x; acc.y = s2 * t0.y;
                acc.z = s2 * t0.z; acc.w = s2 * t0.w;

                int s0 = rowst[node];
                int cnt = deg[node];
                int j = 0;
                for (; j + 4 <= cnt; j += 4) {
                    int2 e0 = csr[s0 + j + 0];
                    int2 e1 = csr[s0 + j + 1];
                    int2 e2 = csr[s0 + j + 2];
                    int2 e3 = csr[s0 + j + 3];
                    float4 r0 = *(const float4*)&hin[(size_t)e0.x * D + c];
                    float4 r1 = *(const float4*)&hin[(size_t)e1.x * D + c];
                    float4 r2 = *(const float4*)&hin[(size_t)e2.x * D + c];
                    float4 r3 = *(const float4*)&hin[(size_t)e3.x * D + c];
                    EDGE_FMA(acc, e0.y, r0);
                    EDGE_FMA(acc, e1.y, r1);
                    EDGE_FMA(acc, e2.y, r2);
                    EDGE_FMA(acc, e3.y, r3);
                }
                for (; j < cnt; ++j) {
                    int2 e = csr[s0 + j];
                    float4 r = *(const float4*)&hin[(size_t)e.x * D + c];
                    EDGE_FMA(acc, e.y, r);
                }
                // one-time fp32 -> bf16 hi/lo conversion, packed LDS store
                unsigned short h0, l0, h1, l1, h2, l2, h3, l3;
                f2hl(acc.x, h0, l0); f2hl(acc.y, h1, l1);
                f2hl(acc.z, h2, l2); f2hl(acc.w, h3, l3);
                unsigned int hw0 = (unsigned int)h0 | ((unsigned int)h1 << 16);
                unsigned int hw1 = (unsigned int)h2 | ((unsigned int)h3 << 16);
                unsigned int lw0 = (unsigned int)l0 | ((unsigned int)l1 << 16);
                unsigned int lw1 = (unsigned int)l2 | ((unsigned int)l3 << 16);
                int u = (p0 >> 1) ^ ((s & 7) << 2);
                *(uint2*)&sHi[s * 64 + u] = make_uint2(hw0, hw1);
                *(uint2*)&sLo[s * 64 + u] = make_uint2(lw0, lw1);
            }
            // pull next node from the block queue
            int nxt;
            if (l32 == 0) nxt = atomicAdd(&sCtr, 1);
            nxt = __shfl(nxt, 0, 32);
            s = nxt;
        }
    }
    __syncthreads();

    // ---- phase 2: pure-MFMA; wave w = col tile w, all 4 row tiles ----
    const int w = threadIdx.x >> 6;          // wave id == col tile (0..7)
    const int lane = threadIdx.x & 63;
    const int q = lane & 15, g = lane >> 4;

    v4f acc[4];
#pragma unroll
    for (int rt = 0; rt < 4; ++rt) acc[rt] = (v4f)0.f;

    const int sw2 = (q & 7) << 2;

#pragma unroll
    for (int ks = 0; ks < 4; ++ks) {
        // W fragments loaded ONCE per ks, reused across 4 row tiles
        const unsigned int* wk = wf + ((size_t)(ks * 8 + w) * 64 + lane) * 8;
        v8s wh = *(const v8s*)(wk);
        v8s wl = *(const v8s*)(wk + 4);
        int u0 = (ks * 16 + g * 4) ^ sw2;
#pragma unroll
        for (int rt = 0; rt < 4; ++rt) {
            int row = rt * 16 + q;
            v8s ah = *(const v8s*)&sHi[row * 64 + u0];
            v8s al = *(const v8s*)&sLo[row * 64 + u0];
            acc[rt] = __builtin_amdgcn_mfma_f32_16x16x32_bf16(ah, wh, acc[rt], 0, 0, 0);
            acc[rt] = __builtin_amdgcn_mfma_f32_16x16x32_bf16(al, wh, acc[rt], 0, 0, 0);
            acc[rt] = __builtin_amdgcn_mfma_f32_16x16x32_bf16(ah, wl, acc[rt], 0, 0, 0);
        }
    }

    // ---- epilogue: bias + ReLU, store. C/D layout: col = q, row = 4g + i ----
    const int col = w * 16 + q;
    const float bv = bias[col];
#pragma unroll
    for (int rt = 0; rt < 4; ++rt) {
        const int growb = nb + rt * 16 + 4 * g;
#pragma unroll
        for (int i = 0; i < 4; ++i) {
            int grow = growb + i;
            if (grow < N) {
                float v = fmaxf(acc[rt][i] + bv, 0.f);
                hout[(size_t)grow * D + col] = v;
            }
        }
    }
}

// ---------------- head: T16 = H @ Wo, then Out = A_norm . T16 + bo ----------------

__global__ __launch_bounds__(256) void k_gemm_out(const float* __restrict__ A,
                                                  const float* __restrict__ Wo,
                                                  float* __restrict__ Out, int M) {
    __shared__ float sW[128 * 16];
    for (int i = threadIdx.x * 4; i < 2048; i += 1024)
        *(float4*)&sW[i] = *(const float4*)&Wo[i];
    __syncthreads();
    int r = blockIdx.x * 16 + (threadIdx.x >> 4);
    int c = threadIdx.x & 15;
    if (r >= M) return;
    const float* arow = A + (size_t)r * D;
    float acc = 0.f;
#pragma unroll
    for (int k4 = 0; k4 < 32; ++k4) {
        float4 h = *(const float4*)&arow[k4 * 4];
        acc = fmaf(h.x, sW[(k4 * 4 + 0) * 16 + c], acc);
        acc = fmaf(h.y, sW[(k4 * 4 + 1) * 16 + c], acc);
        acc = fmaf(h.z, sW[(k4 * 4 + 2) * 16 + c], acc);
        acc = fmaf(h.w, sW[(k4 * 4 + 3) * 16 + c], acc);
    }
    Out[(size_t)r * 16 + c] = acc;
}

__global__ __launch_bounds__(256) void k_aggr_out(const float* __restrict__ T16,
                                                  const int2* __restrict__ csr,
                                                  const int* __restrict__ rowst,
                                                  const int* __restrict__ deg,
                                                  const float* __restrict__ dinv,
                                                  const float* __restrict__ bias,
                                                  float* __restrict__ Out, int N) {
    int node = blockIdx.x * 16 + (threadIdx.x >> 4);
    int c = threadIdx.x & 15;
    if (node >= N) return;
    float di = dinv[node];
    float acc = fmaf(di * di, T16[(size_t)node * 16 + c], bias[c]);
    int s0 = rowst[node];
    int cnt = deg[node];
    int j = 0;
    for (; j + 4 <= cnt; j += 4) {
        int2 e0 = csr[s0 + j + 0];
        int2 e1 = csr[s0 + j + 1];
        int2 e2 = csr[s0 + j + 2];
        int2 e3 = csr[s0 + j + 3];
        float r0 = T16[(size_t)e0.x * 16 + c];
        float r1 = T16[(size_t)e1.x * 16 + c];
        float r2 = T16[(size_t)e2.x * 16 + c];
        float r3 = T16[(size_t)e3.x * 16 + c];
        acc = fmaf(__int_as_float(e0.y), r0, acc);
        acc = fmaf(__int_as_float(e1.y), r1, acc);
        acc = fmaf(__int_as_float(e2.y), r2, acc);
        acc = fmaf(__int_as_float(e3.y), r3, acc);
    }
    for (; j < cnt; ++j) {
        int2 e = csr[s0 + j];
        acc = fmaf(__int_as_float(e.y), T16[(size_t)e.x * 16 + c], acc);
    }
    Out[(size_t)node * 16 + c] = acc;
}

// ---------------- launch ----------------

extern "C" void kernel_launch(void* const* d_in, const int* in_sizes, int n_in,
                              void* d_out, int out_size, void* d_ws, size_t ws_size,
                              hipStream_t stream) {
    const float* x  = (const float*)d_in[0];
    const int*   ei = (const int*)d_in[1];
    const float* Ws = (const float*)d_in[2];
    const float* bs = (const float*)d_in[3];
    const float* Wo = (const float*)d_in[4];
    const float* bo = (const float*)d_in[5];
    float* out = (float*)d_out;

    const int N = in_sizes[0] / D;     // 100000
    const int E = in_sizes[1] / 2;     // 600000
    const int* src = ei;
    const int* dst = ei + E;

    // workspace layout (~109.4 MB)
    float* H0     = (float*)d_ws;                     // N*128 fp32 ping
    float* H1     = H0 + (size_t)N * D;               // N*128 fp32 pong
    int*   deg    = (int*)(H1 + (size_t)N * D);
    int*   cursor = deg + N;
    int*   rowst  = cursor + N;
    float* dinv   = (float*)(rowst + N);
    int*   bsums  = (int*)(dinv + N);
    int2*  csr    = (int2*)(bsums + 1024);
    unsigned int* wfrag = (unsigned int*)(csr + E);   // 9 * 16384 uints (576 KB)

    const int NB = (N + 1023) / 1024;

    hipMemsetAsync(deg, 0, (size_t)2 * N * sizeof(int), stream);  // deg + cursor
    k_count<<<(E + 255) / 256, 256, 0, stream>>>(dst, deg, E);
    k_blocksum<<<NB, 256, 0, stream>>>(deg, bsums, N);
    k_scanbsums<<<1, 256, 0, stream>>>(bsums, NB);
    k_scan2<<<NB, 256, 0, stream>>>(deg, bsums, rowst, dinv, N);
    k_fill<<<(E + 255) / 256, 256, 0, stream>>>(src, dst, rowst, cursor, dinv, csr, E);

    k_wconv<<<288, 64, 0, stream>>>(Ws, wfrag);

    const float* hin = x;
    float* hout = H0;
    const int gblk64 = (N + 63) / 64;
    for (int l = 0; l < 9; ++l) {
        k_fused<<<gblk64, 512, 0, stream>>>(hin, csr, rowst, deg, dinv,
                                            wfrag + (size_t)l * 16384,
                                            bs + (size_t)l * D, hout, N);
        hin = hout;
        hout = (hout == H0) ? H1 : H0;
    }
    // head: transform-then-aggregate (16-wide gather, 8x fewer bytes)
    float* T16 = hout;                 // reuse the other ping-pong buffer
    k_gemm_out<<<(N + 15) / 16, 256, 0, stream>>>(hin, Wo, T16, N);
    k_aggr_out<<<(N + 15) / 16, 256, 0, stream>>>(T16, csr, rowst, deg, dinv, bo, out, N);
}

// Round 18
// 603.609 us; speedup vs baseline: 1.4084x; 1.3006x over previous
//
#include <hip/hip_runtime.h>
#include <hip/hip_fp16.h>

#define D 128

typedef short v8s __attribute__((ext_vector_type(8)));
typedef float v4f __attribute__((ext_vector_type(4)));

// fp32 -> bf16 hi/lo split: f ~= hi + lo, |err| ~ 2^-17 * |f|
__device__ __forceinline__ void f2hl(float f, unsigned short& h, unsigned short& l) {
    unsigned int u = __float_as_uint(f);
    unsigned int hu = u & 0xffff0000u;
    float lf = f - __uint_as_float(hu);          // exact
    h = (unsigned short)(hu >> 16);
    l = (unsigned short)((__float_as_uint(lf) + 0x8000u) >> 16);  // round
}

__device__ __forceinline__ float h2f(unsigned short u) {
    __half h;
    __builtin_memcpy(&h, &u, 2);
    return __half2float(h);
}
__device__ __forceinline__ unsigned short f2h(float f) {
    __half h = __float2half(f);
    unsigned short u;
    __builtin_memcpy(&u, &h, 2);
    return u;
}

// permuted column position for a 4-aligned k chunk (MFMA A-frag contiguous layout)
// k = 4g + (e&3) + 16*(e>>2)  <->  p = 8g + e   (within each 32-wide k block)
__device__ __forceinline__ int permc(int c) {
    return (c & ~31) + ((c & 12) << 1) + ((c & 16) >> 2);
}

// ---------------- preprocessing ----------------

__global__ void k_count(const int* __restrict__ dst, int* __restrict__ deg, int E) {
    int e = blockIdx.x * 256 + threadIdx.x;
    if (e < E) atomicAdd(&deg[dst[e]], 1);
}

__global__ __launch_bounds__(256) void k_blocksum(const int* __restrict__ deg,
                                                  int* __restrict__ bsums, int N) {
    __shared__ int s[256];
    int base = blockIdx.x * 1024 + threadIdx.x * 4;
    int v = 0;
#pragma unroll
    for (int j = 0; j < 4; ++j) { int i = base + j; if (i < N) v += deg[i]; }
    s[threadIdx.x] = v;
    __syncthreads();
    for (int off = 128; off > 0; off >>= 1) {
        if (threadIdx.x < off) s[threadIdx.x] += s[threadIdx.x + off];
        __syncthreads();
    }
    if (threadIdx.x == 0) bsums[blockIdx.x] = s[0];
}

__global__ __launch_bounds__(256) void k_scanbsums(int* __restrict__ bsums, int NB) {
    __shared__ int s[256];
    __shared__ int carry;
    int t = threadIdx.x;
    if (t == 0) carry = 0;
    __syncthreads();
    for (int base = 0; base < NB; base += 256) {
        int i = base + t;
        int v = (i < NB) ? bsums[i] : 0;
        s[t] = v;
        __syncthreads();
        for (int off = 1; off < 256; off <<= 1) {
            int x = (t >= off) ? s[t - off] : 0;
            __syncthreads();
            s[t] += x;
            __syncthreads();
        }
        if (i < NB) bsums[i] = carry + s[t] - v;   // exclusive
        __syncthreads();
        if (t == 0) carry += s[255];
        __syncthreads();
    }
}

__global__ __launch_bounds__(256) void k_scan2(const int* __restrict__ deg,
                                               const int* __restrict__ bsums,
                                               int* __restrict__ rowst,
                                               float* __restrict__ dinv, int N) {
    __shared__ int s[256];
    int t = threadIdx.x;
    int base = blockIdx.x * 1024 + t * 4;
    int v[4];
#pragma unroll
    for (int j = 0; j < 4; ++j) { int i = base + j; v[j] = (i < N) ? deg[i] : 0; }
    int tsum = v[0] + v[1] + v[2] + v[3];
    s[t] = tsum;
    __syncthreads();
    for (int off = 1; off < 256; off <<= 1) {
        int x = (t >= off) ? s[t - off] : 0;
        __syncthreads();
        s[t] += x;
        __syncthreads();
    }
    int run = s[t] - tsum + bsums[blockIdx.x];
#pragma unroll
    for (int j = 0; j < 4; ++j) {
        int i = base + j;
        if (i < N) {
            rowst[i] = run;
            dinv[i] = rsqrtf((float)(v[j] + 1));   // +1 for self-loop
        }
        run += v[j];
    }
}

__global__ void k_fill(const int* __restrict__ src, const int* __restrict__ dst,
                       const int* __restrict__ rowst, int* __restrict__ cursor,
                       const float* __restrict__ dinv, int2* __restrict__ csr, int E) {
    int e = blockIdx.x * 256 + threadIdx.x;
    if (e >= E) return;
    int s = src[e], d = dst[e];
    int p = rowst[d] + atomicAdd(&cursor[d], 1);
    csr[p] = make_int2(s, __float_as_int(dinv[s] * dinv[d]));
}

// x fp32 -> fp16 (one-time)
__global__ __launch_bounds__(256) void k_xconv(const float* __restrict__ x,
                                               unsigned short* __restrict__ g, int NE) {
    int i = (blockIdx.x * 256 + threadIdx.x) * 4;
    if (i >= NE) return;
    float4 v = *(const float4*)&x[i];
    ushort4 o;
    o.x = f2h(v.x); o.y = f2h(v.y); o.z = f2h(v.z); o.w = f2h(v.w);
    *(ushort4*)&g[i] = o;
}

// ---------------- weight fragment packing ----------------

// Ws[9][128][128] fp32 -> per-lane MFMA B fragments, hi/lo bf16:
// wf[((l*4+ks)*8+nt)*64 + lane][8 words]: words 0-3 = hi frag, 4-7 = lo frag
__global__ __launch_bounds__(64) void k_wconv(const float* __restrict__ Ws,
                                              unsigned int* __restrict__ wf) {
    int b = blockIdx.x;              // l*32 + ks*8 + nt
    int l = b >> 5, ks = (b >> 3) & 3, nt = b & 7;
    int lane = threadIdx.x;
    int g = lane >> 4, c = (lane & 15) + nt * 16;
    const float* W = Ws + (size_t)l * D * D;
    unsigned int hw[4], lw[4];
#pragma unroll
    for (int w = 0; w < 4; ++w) {
        unsigned short hs[2], ls[2];
#pragma unroll
        for (int j = 0; j < 2; ++j) {
            int e = 2 * w + j;
            int k = ks * 32 + 4 * g + (e & 3) + 16 * (e >> 2);
            f2hl(W[k * D + c], hs[j], ls[j]);
        }
        hw[w] = (unsigned int)hs[0] | ((unsigned int)hs[1] << 16);
        lw[w] = (unsigned int)ls[0] | ((unsigned int)ls[1] << 16);
    }
    unsigned int* dstp = wf + ((size_t)((l * 4 + ks) * 8 + nt) * 64 + lane) * 8;
    *(uint4*)dstp = make_uint4(hw[0], hw[1], hw[2], hw[3]);
    *(uint4*)(dstp + 4) = make_uint4(lw[0], lw[1], lw[2], lw[3]);
}

// ---------------- fused hidden layer: hout = relu( (A_norm . hin) @ W + b ) --------
// hin/hout are fp16 (N x 128) -- HALF the gather bytes of fp32.
// 64-node tile per 512-thread block. Phase 1: 16 groups of 32 lanes pull nodes from
// an LDS work queue (first 16 static); per-node walk: unroll-4, 8B ushort4 loads +
// cvt to fp32, fp32 accumulate; epilogue: bf16 hi/lo split once, packed LDS planes.
// Phase 2: 8 waves; wave w owns col tile w for all 4 row tiles (W frags reused 4x).

#define EDGE_FMA(ACC, EW, R)                                               \
    {                                                                      \
        float w_ = __int_as_float(EW);                                     \
        ACC.x = fmaf(w_, (R).x, ACC.x); ACC.y = fmaf(w_, (R).y, ACC.y);    \
        ACC.z = fmaf(w_, (R).z, ACC.z); ACC.w = fmaf(w_, (R).w, ACC.w);    \
    }

#define CVT4(U) make_float4(h2f((U).x), h2f((U).y), h2f((U).z), h2f((U).w))

__global__ __launch_bounds__(512, 8) void k_fused(const unsigned short* __restrict__ hin,
                                                  const int2* __restrict__ csr,
                                                  const int* __restrict__ rowst,
                                                  const int* __restrict__ deg,
                                                  const float* __restrict__ dinv,
                                                  const unsigned int* __restrict__ wf,
                                                  const float* __restrict__ bias,
                                                  unsigned short* __restrict__ hout,
                                                  int N) {
    __shared__ unsigned int sHi[64 * 64];    // 16 KB bf16-hi plane (64 rows x 64 uints)
    __shared__ unsigned int sLo[64 * 64];    // 16 KB bf16-lo plane
    __shared__ int sCtr;
    const int nb = blockIdx.x * 64;

    if (threadIdx.x == 0) sCtr = 16;
    __syncthreads();

    // ---- phase 1: groups pull nodes dynamically; one node at a time ----
    {
        const int gp = threadIdx.x >> 5;     // 0..15
        const int l32 = threadIdx.x & 31;
        const int c = l32 << 2;
        const int p0 = permc(c);
        int s = gp;                          // first 16 rows statically assigned
        while (s < 64) {
            int node = nb + s;
            if (node < N) {
                float di = dinv[node];
                float s2 = di * di;
                ushort4 tu = *(const ushort4*)&hin[(size_t)node * D + c];
                float4 t0 = CVT4(tu);
                float4 acc;
                acc.x = s2 * t0.x; acc.y = s2 * t0.y;
                acc.z = s2 * t0.z; acc.w = s2 * t0.w;

                int s0 = rowst[node];
                int cnt = deg[node];
                int j = 0;
                for (; j + 4 <= cnt; j += 4) {
                    int2 e0 = csr[s0 + j + 0];
                    int2 e1 = csr[s0 + j + 1];
                    int2 e2 = csr[s0 + j + 2];
                    int2 e3 = csr[s0 + j + 3];
                    ushort4 u0 = *(const ushort4*)&hin[(size_t)e0.x * D + c];
                    ushort4 u1 = *(const ushort4*)&hin[(size_t)e1.x * D + c];
                    ushort4 u2 = *(const ushort4*)&hin[(size_t)e2.x * D + c];
                    ushort4 u3 = *(const ushort4*)&hin[(size_t)e3.x * D + c];
                    float4 r0 = CVT4(u0);
                    float4 r1 = CVT4(u1);
                    float4 r2 = CVT4(u2);
                    float4 r3 = CVT4(u3);
                    EDGE_FMA(acc, e0.y, r0);
                    EDGE_FMA(acc, e1.y, r1);
                    EDGE_FMA(acc, e2.y, r2);
                    EDGE_FMA(acc, e3.y, r3);
                }
                for (; j < cnt; ++j) {
                    int2 e = csr[s0 + j];
                    ushort4 u = *(const ushort4*)&hin[(size_t)e.x * D + c];
                    float4 r = CVT4(u);
                    EDGE_FMA(acc, e.y, r);
                }
                // one-time fp32 -> bf16 hi/lo conversion, packed LDS store
                unsigned short h0, l0, h1, l1, h2, l2, h3, l3;
                f2hl(acc.x, h0, l0); f2hl(acc.y, h1, l1);
                f2hl(acc.z, h2, l2); f2hl(acc.w, h3, l3);
                unsigned int hw0 = (unsigned int)h0 | ((unsigned int)h1 << 16);
                unsigned int hw1 = (unsigned int)h2 | ((unsigned int)h3 << 16);
                unsigned int lw0 = (unsigned int)l0 | ((unsigned int)l1 << 16);
                unsigned int lw1 = (unsigned int)l2 | ((unsigned int)l3 << 16);
                int u = (p0 >> 1) ^ ((s & 7) << 2);
                *(uint2*)&sHi[s * 64 + u] = make_uint2(hw0, hw1);
                *(uint2*)&sLo[s * 64 + u] = make_uint2(lw0, lw1);
            }
            // pull next node from the block queue
            int nxt;
            if (l32 == 0) nxt = atomicAdd(&sCtr, 1);
            nxt = __shfl(nxt, 0, 32);
            s = nxt;
        }
    }
    __syncthreads();

    // ---- phase 2: pure-MFMA; wave w = col tile w, all 4 row tiles ----
    const int w = threadIdx.x >> 6;          // wave id == col tile (0..7)
    const int lane = threadIdx.x & 63;
    const int q = lane & 15, g = lane >> 4;

    v4f acc[4];
#pragma unroll
    for (int rt = 0; rt < 4; ++rt) acc[rt] = (v4f)0.f;

    const int sw2 = (q & 7) << 2;

#pragma unroll
    for (int ks = 0; ks < 4; ++ks) {
        // W fragments loaded ONCE per ks, reused across 4 row tiles
        const unsigned int* wk = wf + ((size_t)(ks * 8 + w) * 64 + lane) * 8;
        v8s wh = *(const v8s*)(wk);
        v8s wl = *(const v8s*)(wk + 4);
        int u0 = (ks * 16 + g * 4) ^ sw2;
#pragma unroll
        for (int rt = 0; rt < 4; ++rt) {
            int row = rt * 16 + q;
            v8s ah = *(const v8s*)&sHi[row * 64 + u0];
            v8s al = *(const v8s*)&sLo[row * 64 + u0];
            acc[rt] = __builtin_amdgcn_mfma_f32_16x16x32_bf16(ah, wh, acc[rt], 0, 0, 0);
            acc[rt] = __builtin_amdgcn_mfma_f32_16x16x32_bf16(al, wh, acc[rt], 0, 0, 0);
            acc[rt] = __builtin_amdgcn_mfma_f32_16x16x32_bf16(ah, wl, acc[rt], 0, 0, 0);
        }
    }

    // ---- epilogue: bias + ReLU, fp16 store. C/D layout: col = q, row = 4g + i ----
    const int col = w * 16 + q;
    const float bv = bias[col];
#pragma unroll
    for (int rt = 0; rt < 4; ++rt) {
        const int growb = nb + rt * 16 + 4 * g;
#pragma unroll
        for (int i = 0; i < 4; ++i) {
            int grow = growb + i;
            if (grow < N) {
                float v = fmaxf(acc[rt][i] + bv, 0.f);
                hout[(size_t)grow * D + col] = f2h(v);
            }
        }
    }
}

// ---------------- head: T16 = H @ Wo, then Out = A_norm . T16 + bo ----------------

__global__ __launch_bounds__(256) void k_gemm_out(const unsigned short* __restrict__ A,
                                                  const float* __restrict__ Wo,
                                                  float* __restrict__ Out, int M) {
    __shared__ float sW[128 * 16];
    for (int i = threadIdx.x * 4; i < 2048; i += 1024)
        *(float4*)&sW[i] = *(const float4*)&Wo[i];
    __syncthreads();
    int r = blockIdx.x * 16 + (threadIdx.x >> 4);
    int c = threadIdx.x & 15;
    if (r >= M) return;
    const unsigned short* arow = A + (size_t)r * D;
    float acc = 0.f;
#pragma unroll
    for (int k4 = 0; k4 < 32; ++k4) {
        ushort4 hq = *(const ushort4*)&arow[k4 * 4];
        acc = fmaf(h2f(hq.x), sW[(k4 * 4 + 0) * 16 + c], acc);
        acc = fmaf(h2f(hq.y), sW[(k4 * 4 + 1) * 16 + c], acc);
        acc = fmaf(h2f(hq.z), sW[(k4 * 4 + 2) * 16 + c], acc);
        acc = fmaf(h2f(hq.w), sW[(k4 * 4 + 3) * 16 + c], acc);
    }
    Out[(size_t)r * 16 + c] = acc;
}

__global__ __launch_bounds__(256) void k_aggr_out(const float* __restrict__ T16,
                                                  const int2* __restrict__ csr,
                                                  const int* __restrict__ rowst,
                                                  const int* __restrict__ deg,
                                                  const float* __restrict__ dinv,
                                                  const float* __restrict__ bias,
                                                  float* __restrict__ Out, int N) {
    int node = blockIdx.x * 16 + (threadIdx.x >> 4);
    int c = threadIdx.x & 15;
    if (node >= N) return;
    float di = dinv[node];
    float acc = fmaf(di * di, T16[(size_t)node * 16 + c], bias[c]);
    int s0 = rowst[node];
    int cnt = deg[node];
    int j = 0;
    for (; j + 4 <= cnt; j += 4) {
        int2 e0 = csr[s0 + j + 0];
        int2 e1 = csr[s0 + j + 1];
        int2 e2 = csr[s0 + j + 2];
        int2 e3 = csr[s0 + j + 3];
        float r0 = T16[(size_t)e0.x * 16 + c];
        float r1 = T16[(size_t)e1.x * 16 + c];
        float r2 = T16[(size_t)e2.x * 16 + c];
        float r3 = T16[(size_t)e3.x * 16 + c];
        acc = fmaf(__int_as_float(e0.y), r0, acc);
        acc = fmaf(__int_as_float(e1.y), r1, acc);
        acc = fmaf(__int_as_float(e2.y), r2, acc);
        acc = fmaf(__int_as_float(e3.y), r3, acc);
    }
    for (; j < cnt; ++j) {
        int2 e = csr[s0 + j];
        acc = fmaf(__int_as_float(e.y), T16[(size_t)e.x * 16 + c], acc);
    }
    Out[(size_t)node * 16 + c] = acc;
}

// ---------------- launch ----------------

extern "C" void kernel_launch(void* const* d_in, const int* in_sizes, int n_in,
                              void* d_out, int out_size, void* d_ws, size_t ws_size,
                              hipStream_t stream) {
    const float* x  = (const float*)d_in[0];
    const int*   ei = (const int*)d_in[1];
    const float* Ws = (const float*)d_in[2];
    const float* bs = (const float*)d_in[3];
    const float* Wo = (const float*)d_in[4];
    const float* bo = (const float*)d_in[5];
    float* out = (float*)d_out;

    const int N = in_sizes[0] / D;     // 100000
    const int E = in_sizes[1] / 2;     // 600000
    const int* src = ei;
    const int* dst = ei + E;

    // workspace layout (~65 MB)
    unsigned short* G0 = (unsigned short*)d_ws;       // N*128 fp16 ping (25.6 MB)
    unsigned short* G1 = G0 + (size_t)N * D;          // N*128 fp16 pong
    float* T16    = (float*)(G1 + (size_t)N * D);     // N*16 fp32 head temp
    int*   deg    = (int*)(T16 + (size_t)N * 16);
    int*   cursor = deg + N;
    int*   rowst  = cursor + N;
    float* dinv   = (float*)(rowst + N);
    int*   bsums  = (int*)(dinv + N);
    int2*  csr    = (int2*)(bsums + 1024);
    unsigned int* wfrag = (unsigned int*)(csr + E);   // 9 * 16384 uints (576 KB)

    const int NB = (N + 1023) / 1024;

    hipMemsetAsync(deg, 0, (size_t)2 * N * sizeof(int), stream);  // deg + cursor
    k_count<<<(E + 255) / 256, 256, 0, stream>>>(dst, deg, E);
    k_blocksum<<<NB, 256, 0, stream>>>(deg, bsums, N);
    k_scanbsums<<<1, 256, 0, stream>>>(bsums, NB);
    k_scan2<<<NB, 256, 0, stream>>>(deg, bsums, rowst, dinv, N);
    k_fill<<<(E + 255) / 256, 256, 0, stream>>>(src, dst, rowst, cursor, dinv, csr, E);

    k_wconv<<<288, 64, 0, stream>>>(Ws, wfrag);
    k_xconv<<<(N * D / 4 + 255) / 256, 256, 0, stream>>>(x, G0, N * D);

    const unsigned short* hin = G0;
    unsigned short* hout = G1;
    const int gblk64 = (N + 63) / 64;
    for (int l = 0; l < 9; ++l) {
        k_fused<<<gblk64, 512, 0, stream>>>(hin, csr, rowst, deg, dinv,
                                            wfrag + (size_t)l * 16384,
                                            bs + (size_t)l * D, hout, N);
        hin = hout;
        hout = (hout == G0) ? G0 == hout ? G1 : G0 : G0;  // swap
        hout = (hin == G0) ? G1 : G0;
    }
    // head: transform-then-aggregate (16-wide gather)
    k_gemm_out<<<(N + 15) / 16, 256, 0, stream>>>(hin, Wo, T16, N);
    k_aggr_out<<<(N + 15) / 16, 256, 0, stream>>>(T16, csr, rowst, deg, dinv, bo, out, N);
}

// Round 19
// 558.512 us; speedup vs baseline: 1.5221x; 1.0807x over previous
//
#include <hip/hip_runtime.h>
#include <hip/hip_fp16.h>

#define D 128

typedef short v8s __attribute__((ext_vector_type(8)));
typedef float v4f __attribute__((ext_vector_type(4)));
typedef unsigned short u16x8 __attribute__((ext_vector_type(8)));

// fp32 -> bf16 hi/lo split: f ~= hi + lo, |err| ~ 2^-17 * |f|
__device__ __forceinline__ void f2hl(float f, unsigned short& h, unsigned short& l) {
    unsigned int u = __float_as_uint(f);
    unsigned int hu = u & 0xffff0000u;
    float lf = f - __uint_as_float(hu);          // exact
    h = (unsigned short)(hu >> 16);
    l = (unsigned short)((__float_as_uint(lf) + 0x8000u) >> 16);  // round
}

__device__ __forceinline__ float h2f(unsigned short u) {
    __half h;
    __builtin_memcpy(&h, &u, 2);
    return __half2float(h);
}
__device__ __forceinline__ unsigned short f2h(float f) {
    __half h = __float2half(f);
    unsigned short u;
    __builtin_memcpy(&u, &h, 2);
    return u;
}

// permuted column position for a 4-aligned k chunk (MFMA A-frag contiguous layout)
// k = 4g + (e&3) + 16*(e>>2)  <->  p = 8g + e   (within each 32-wide k block)
__device__ __forceinline__ int permc(int c) {
    return (c & ~31) + ((c & 12) << 1) + ((c & 16) >> 2);
}

// ---------------- preprocessing ----------------

__global__ void k_count(const int* __restrict__ dst, int* __restrict__ deg, int E) {
    int e = blockIdx.x * 256 + threadIdx.x;
    if (e < E) atomicAdd(&deg[dst[e]], 1);
}

__global__ __launch_bounds__(256) void k_blocksum(const int* __restrict__ deg,
                                                  int* __restrict__ bsums, int N) {
    __shared__ int s[256];
    int base = blockIdx.x * 1024 + threadIdx.x * 4;
    int v = 0;
#pragma unroll
    for (int j = 0; j < 4; ++j) { int i = base + j; if (i < N) v += deg[i]; }
    s[threadIdx.x] = v;
    __syncthreads();
    for (int off = 128; off > 0; off >>= 1) {
        if (threadIdx.x < off) s[threadIdx.x] += s[threadIdx.x + off];
        __syncthreads();
    }
    if (threadIdx.x == 0) bsums[blockIdx.x] = s[0];
}

__global__ __launch_bounds__(256) void k_scanbsums(int* __restrict__ bsums, int NB) {
    __shared__ int s[256];
    __shared__ int carry;
    int t = threadIdx.x;
    if (t == 0) carry = 0;
    __syncthreads();
    for (int base = 0; base < NB; base += 256) {
        int i = base + t;
        int v = (i < NB) ? bsums[i] : 0;
        s[t] = v;
        __syncthreads();
        for (int off = 1; off < 256; off <<= 1) {
            int x = (t >= off) ? s[t - off] : 0;
            __syncthreads();
            s[t] += x;
            __syncthreads();
        }
        if (i < NB) bsums[i] = carry + s[t] - v;   // exclusive
        __syncthreads();
        if (t == 0) carry += s[255];
        __syncthreads();
    }
}

__global__ __launch_bounds__(256) void k_scan2(const int* __restrict__ deg,
                                               const int* __restrict__ bsums,
                                               int* __restrict__ rowst,
                                               float* __restrict__ dinv, int N) {
    __shared__ int s[256];
    int t = threadIdx.x;
    int base = blockIdx.x * 1024 + t * 4;
    int v[4];
#pragma unroll
    for (int j = 0; j < 4; ++j) { int i = base + j; v[j] = (i < N) ? deg[i] : 0; }
    int tsum = v[0] + v[1] + v[2] + v[3];
    s[t] = tsum;
    __syncthreads();
    for (int off = 1; off < 256; off <<= 1) {
        int x = (t >= off) ? s[t - off] : 0;
        __syncthreads();
        s[t] += x;
        __syncthreads();
    }
    int run = s[t] - tsum + bsums[blockIdx.x];
#pragma unroll
    for (int j = 0; j < 4; ++j) {
        int i = base + j;
        if (i < N) {
            rowst[i] = run;
            dinv[i] = rsqrtf((float)(v[j] + 1));   // +1 for self-loop
        }
        run += v[j];
    }
}

__global__ void k_fill(const int* __restrict__ src, const int* __restrict__ dst,
                       const int* __restrict__ rowst, int* __restrict__ cursor,
                       const float* __restrict__ dinv, int2* __restrict__ csr, int E) {
    int e = blockIdx.x * 256 + threadIdx.x;
    if (e >= E) return;
    int s = src[e], d = dst[e];
    int p = rowst[d] + atomicAdd(&cursor[d], 1);
    csr[p] = make_int2(s, __float_as_int(dinv[s] * dinv[d]));
}

// x fp32 -> fp16 (one-time)
__global__ __launch_bounds__(256) void k_xconv(const float* __restrict__ x,
                                               unsigned short* __restrict__ g, int NE) {
    int i = (blockIdx.x * 256 + threadIdx.x) * 4;
    if (i >= NE) return;
    float4 v = *(const float4*)&x[i];
    ushort4 o;
    o.x = f2h(v.x); o.y = f2h(v.y); o.z = f2h(v.z); o.w = f2h(v.w);
    *(ushort4*)&g[i] = o;
}

// ---------------- weight fragment packing ----------------

// Ws[9][128][128] fp32 -> per-lane MFMA B fragments, hi/lo bf16:
// wf[((l*4+ks)*8+nt)*64 + lane][8 words]: words 0-3 = hi frag, 4-7 = lo frag
__global__ __launch_bounds__(64) void k_wconv(const float* __restrict__ Ws,
                                              unsigned int* __restrict__ wf) {
    int b = blockIdx.x;              // l*32 + ks*8 + nt
    int l = b >> 5, ks = (b >> 3) & 3, nt = b & 7;
    int lane = threadIdx.x;
    int g = lane >> 4, c = (lane & 15) + nt * 16;
    const float* W = Ws + (size_t)l * D * D;
    unsigned int hw[4], lw[4];
#pragma unroll
    for (int w = 0; w < 4; ++w) {
        unsigned short hs[2], ls[2];
#pragma unroll
        for (int j = 0; j < 2; ++j) {
            int e = 2 * w + j;
            int k = ks * 32 + 4 * g + (e & 3) + 16 * (e >> 2);
            f2hl(W[k * D + c], hs[j], ls[j]);
        }
        hw[w] = (unsigned int)hs[0] | ((unsigned int)hs[1] << 16);
        lw[w] = (unsigned int)ls[0] | ((unsigned int)ls[1] << 16);
    }
    unsigned int* dstp = wf + ((size_t)((l * 4 + ks) * 8 + nt) * 64 + lane) * 8;
    *(uint4*)dstp = make_uint4(hw[0], hw[1], hw[2], hw[3]);
    *(uint4*)(dstp + 4) = make_uint4(lw[0], lw[1], lw[2], lw[3]);
}

// ---------------- fused hidden layer: hout = relu( (A_norm . hin) @ W + b ) --------
// hin/hout are fp16 (N x 128). 64-node tile per 512-thread block.
// Phase 1: 32 groups of 16 LANES (16B ushort8 loads -- request-size sweet spot; a
// wave carries 4 concurrent nodes x unroll-4 = 16 row-loads in flight). Groups pull
// nodes from an LDS work queue (first 32 static). fp32 accumulate; epilogue does the
// bf16 hi/lo split once and stores packed planes to LDS.
// Phase 2: 8 waves; wave w owns col tile w for all 4 row tiles (W frags reused 4x).

__device__ __forceinline__ void edge_fma8(float* acc, int ew, u16x8 u) {
    float w_ = __int_as_float(ew);
#pragma unroll
    for (int k = 0; k < 8; ++k)
        acc[k] = fmaf(w_, h2f((unsigned short)u[k]), acc[k]);
}

__global__ __launch_bounds__(512, 8) void k_fused(const unsigned short* __restrict__ hin,
                                                  const int2* __restrict__ csr,
                                                  const int* __restrict__ rowst,
                                                  const int* __restrict__ deg,
                                                  const float* __restrict__ dinv,
                                                  const unsigned int* __restrict__ wf,
                                                  const float* __restrict__ bias,
                                                  unsigned short* __restrict__ hout,
                                                  int N) {
    __shared__ unsigned int sHi[64 * 64];    // 16 KB bf16-hi plane (64 rows x 64 uints)
    __shared__ unsigned int sLo[64 * 64];    // 16 KB bf16-lo plane
    __shared__ int sCtr;
    const int nb = blockIdx.x * 64;

    if (threadIdx.x == 0) sCtr = 32;
    __syncthreads();

    // ---- phase 1: 16-lane groups pull nodes dynamically; one node at a time ----
    {
        const int gp = threadIdx.x >> 4;     // 0..31
        const int l16 = threadIdx.x & 15;
        const int c = l16 << 3;              // 8 fp16 per lane
        const int u1 = permc(c) >> 1;        // uint offset of first 4-chunk
        const int u2 = permc(c + 4) >> 1;    // uint offset of second 4-chunk
        int s = gp;                          // first 32 rows statically assigned
        while (s < 64) {
            int node = nb + s;
            if (node < N) {
                float di = dinv[node];
                float s2 = di * di;
                u16x8 tu = *(const u16x8*)&hin[(size_t)node * D + c];
                float acc[8];
#pragma unroll
                for (int k = 0; k < 8; ++k) acc[k] = s2 * h2f((unsigned short)tu[k]);

                int s0 = rowst[node];
                int cnt = deg[node];
                int j = 0;
                for (; j + 4 <= cnt; j += 4) {
                    int2 e0 = csr[s0 + j + 0];
                    int2 e1 = csr[s0 + j + 1];
                    int2 e2 = csr[s0 + j + 2];
                    int2 e3 = csr[s0 + j + 3];
                    u16x8 r0 = *(const u16x8*)&hin[(size_t)e0.x * D + c];
                    u16x8 r1 = *(const u16x8*)&hin[(size_t)e1.x * D + c];
                    u16x8 r2 = *(const u16x8*)&hin[(size_t)e2.x * D + c];
                    u16x8 r3 = *(const u16x8*)&hin[(size_t)e3.x * D + c];
                    edge_fma8(acc, e0.y, r0);
                    edge_fma8(acc, e1.y, r1);
                    edge_fma8(acc, e2.y, r2);
                    edge_fma8(acc, e3.y, r3);
                }
                for (; j < cnt; ++j) {
                    int2 e = csr[s0 + j];
                    u16x8 r = *(const u16x8*)&hin[(size_t)e.x * D + c];
                    edge_fma8(acc, e.y, r);
                }
                // one-time fp32 -> bf16 hi/lo conversion, packed LDS store
                unsigned short h[8], l[8];
#pragma unroll
                for (int k = 0; k < 8; ++k) f2hl(acc[k], h[k], l[k]);
                unsigned int hw0 = (unsigned int)h[0] | ((unsigned int)h[1] << 16);
                unsigned int hw1 = (unsigned int)h[2] | ((unsigned int)h[3] << 16);
                unsigned int hw2 = (unsigned int)h[4] | ((unsigned int)h[5] << 16);
                unsigned int hw3 = (unsigned int)h[6] | ((unsigned int)h[7] << 16);
                unsigned int lw0 = (unsigned int)l[0] | ((unsigned int)l[1] << 16);
                unsigned int lw1 = (unsigned int)l[2] | ((unsigned int)l[3] << 16);
                unsigned int lw2 = (unsigned int)l[4] | ((unsigned int)l[5] << 16);
                unsigned int lw3 = (unsigned int)l[6] | ((unsigned int)l[7] << 16);
                int sw = (s & 7) << 2;
                int a1 = u1 ^ sw, a2 = u2 ^ sw;
                *(uint2*)&sHi[s * 64 + a1] = make_uint2(hw0, hw1);
                *(uint2*)&sHi[s * 64 + a2] = make_uint2(hw2, hw3);
                *(uint2*)&sLo[s * 64 + a1] = make_uint2(lw0, lw1);
                *(uint2*)&sLo[s * 64 + a2] = make_uint2(lw2, lw3);
            }
            // pull next node from the block queue
            int nxt;
            if (l16 == 0) nxt = atomicAdd(&sCtr, 1);
            nxt = __shfl(nxt, 0, 16);
            s = nxt;
        }
    }
    __syncthreads();

    // ---- phase 2: pure-MFMA; wave w = col tile w, all 4 row tiles ----
    const int w = threadIdx.x >> 6;          // wave id == col tile (0..7)
    const int lane = threadIdx.x & 63;
    const int q = lane & 15, g = lane >> 4;

    v4f acc[4];
#pragma unroll
    for (int rt = 0; rt < 4; ++rt) acc[rt] = (v4f)0.f;

    const int sw2 = (q & 7) << 2;

#pragma unroll
    for (int ks = 0; ks < 4; ++ks) {
        // W fragments loaded ONCE per ks, reused across 4 row tiles
        const unsigned int* wk = wf + ((size_t)(ks * 8 + w) * 64 + lane) * 8;
        v8s wh = *(const v8s*)(wk);
        v8s wl = *(const v8s*)(wk + 4);
        int u0 = (ks * 16 + g * 4) ^ sw2;
#pragma unroll
        for (int rt = 0; rt < 4; ++rt) {
            int row = rt * 16 + q;
            v8s ah = *(const v8s*)&sHi[row * 64 + u0];
            v8s al = *(const v8s*)&sLo[row * 64 + u0];
            acc[rt] = __builtin_amdgcn_mfma_f32_16x16x32_bf16(ah, wh, acc[rt], 0, 0, 0);
            acc[rt] = __builtin_amdgcn_mfma_f32_16x16x32_bf16(al, wh, acc[rt], 0, 0, 0);
            acc[rt] = __builtin_amdgcn_mfma_f32_16x16x32_bf16(ah, wl, acc[rt], 0, 0, 0);
        }
    }

    // ---- epilogue: bias + ReLU, fp16 store. C/D layout: col = q, row = 4g + i ----
    const int col = w * 16 + q;
    const float bv = bias[col];
#pragma unroll
    for (int rt = 0; rt < 4; ++rt) {
        const int growb = nb + rt * 16 + 4 * g;
#pragma unroll
        for (int i = 0; i < 4; ++i) {
            int grow = growb + i;
            if (grow < N) {
                float v = fmaxf(acc[rt][i] + bv, 0.f);
                hout[(size_t)grow * D + col] = f2h(v);
            }
        }
    }
}

// ---------------- head: T16 = H @ Wo, then Out = A_norm . T16 + bo ----------------

__global__ __launch_bounds__(256) void k_gemm_out(const unsigned short* __restrict__ A,
                                                  const float* __restrict__ Wo,
                                                  float* __restrict__ Out, int M) {
    __shared__ float sW[128 * 16];
    for (int i = threadIdx.x * 4; i < 2048; i += 1024)
        *(float4*)&sW[i] = *(const float4*)&Wo[i];
    __syncthreads();
    int r = blockIdx.x * 16 + (threadIdx.x >> 4);
    int c = threadIdx.x & 15;
    if (r >= M) return;
    const unsigned short* arow = A + (size_t)r * D;
    float acc = 0.f;
#pragma unroll
    for (int k4 = 0; k4 < 32; ++k4) {
        ushort4 hq = *(const ushort4*)&arow[k4 * 4];
        acc = fmaf(h2f(hq.x), sW[(k4 * 4 + 0) * 16 + c], acc);
        acc = fmaf(h2f(hq.y), sW[(k4 * 4 + 1) * 16 + c], acc);
        acc = fmaf(h2f(hq.z), sW[(k4 * 4 + 2) * 16 + c], acc);
        acc = fmaf(h2f(hq.w), sW[(k4 * 4 + 3) * 16 + c], acc);
    }
    Out[(size_t)r * 16 + c] = acc;
}

__global__ __launch_bounds__(256) void k_aggr_out(const float* __restrict__ T16,
                                                  const int2* __restrict__ csr,
                                                  const int* __restrict__ rowst,
                                                  const int* __restrict__ deg,
                                                  const float* __restrict__ dinv,
                                                  const float* __restrict__ bias,
                                                  float* __restrict__ Out, int N) {
    int node = blockIdx.x * 16 + (threadIdx.x >> 4);
    int c = threadIdx.x & 15;
    if (node >= N) return;
    float di = dinv[node];
    float acc = fmaf(di * di, T16[(size_t)node * 16 + c], bias[c]);
    int s0 = rowst[node];
    int cnt = deg[node];
    int j = 0;
    for (; j + 4 <= cnt; j += 4) {
        int2 e0 = csr[s0 + j + 0];
        int2 e1 = csr[s0 + j + 1];
        int2 e2 = csr[s0 + j + 2];
        int2 e3 = csr[s0 + j + 3];
        float r0 = T16[(size_t)e0.x * 16 + c];
        float r1 = T16[(size_t)e1.x * 16 + c];
        float r2 = T16[(size_t)e2.x * 16 + c];
        float r3 = T16[(size_t)e3.x * 16 + c];
        acc = fmaf(__int_as_float(e0.y), r0, acc);
        acc = fmaf(__int_as_float(e1.y), r1, acc);
        acc = fmaf(__int_as_float(e2.y), r2, acc);
        acc = fmaf(__int_as_float(e3.y), r3, acc);
    }
    for (; j < cnt; ++j) {
        int2 e = csr[s0 + j];
        acc = fmaf(__int_as_float(e.y), T16[(size_t)e.x * 16 + c], acc);
    }
    Out[(size_t)node * 16 + c] = acc;
}

// ---------------- launch ----------------

extern "C" void kernel_launch(void* const* d_in, const int* in_sizes, int n_in,
                              void* d_out, int out_size, void* d_ws, size_t ws_size,
                              hipStream_t stream) {
    const float* x  = (const float*)d_in[0];
    const int*   ei = (const int*)d_in[1];
    const float* Ws = (const float*)d_in[2];
    const float* bs = (const float*)d_in[3];
    const float* Wo = (const float*)d_in[4];
    const float* bo = (const float*)d_in[5];
    float* out = (float*)d_out;

    const int N = in_sizes[0] / D;     // 100000
    const int E = in_sizes[1] / 2;     // 600000
    const int* src = ei;
    const int* dst = ei + E;

    // workspace layout (~65 MB)
    unsigned short* G0 = (unsigned short*)d_ws;       // N*128 fp16 ping (25.6 MB)
    unsigned short* G1 = G0 + (size_t)N * D;          // N*128 fp16 pong
    float* T16    = (float*)(G1 + (size_t)N * D);     // N*16 fp32 head temp
    int*   deg    = (int*)(T16 + (size_t)N * 16);
    int*   cursor = deg + N;
    int*   rowst  = cursor + N;
    float* dinv   = (float*)(rowst + N);
    int*   bsums  = (int*)(dinv + N);
    int2*  csr    = (int2*)(bsums + 1024);
    unsigned int* wfrag = (unsigned int*)(csr + E);   // 9 * 16384 uints (576 KB)

    const int NB = (N + 1023) / 1024;

    hipMemsetAsync(deg, 0, (size_t)2 * N * sizeof(int), stream);  // deg + cursor
    k_count<<<(E + 255) / 256, 256, 0, stream>>>(dst, deg, E);
    k_blocksum<<<NB, 256, 0, stream>>>(deg, bsums, N);
    k_scanbsums<<<1, 256, 0, stream>>>(bsums, NB);
    k_scan2<<<NB, 256, 0, stream>>>(deg, bsums, rowst, dinv, N);
    k_fill<<<(E + 255) / 256, 256, 0, stream>>>(src, dst, rowst, cursor, dinv, csr, E);

    k_wconv<<<288, 64, 0, stream>>>(Ws, wfrag);
    k_xconv<<<(N * D / 4 + 255) / 256, 256, 0, stream>>>(x, G0, N * D);

    const unsigned short* hin = G0;
    unsigned short* hout = G1;
    const int gblk64 = (N + 63) / 64;
    for (int l = 0; l < 9; ++l) {
        k_fused<<<gblk64, 512, 0, stream>>>(hin, csr, rowst, deg, dinv,
                                            wfrag + (size_t)l * 16384,
                                            bs + (size_t)l * D, hout, N);
        hin = hout;
        hout = (hin == G0) ? G1 : G0;
    }
    // head: transform-then-aggregate (16-wide gather)
    k_gemm_out<<<(N + 15) / 16, 256, 0, stream>>>(hin, Wo, T16, N);
    k_aggr_out<<<(N + 15) / 16, 256, 0, stream>>>(T16, csr, rowst, deg, dinv, bo, out, N);
}